// Round 5
// baseline (56936.322 us; speedup 1.0000x reference)
//
#include <hip/hip_runtime.h>
#include <cmath>

namespace {

constexpr int B_ = 8, L_ = 128, IN_ = 64, H_ = 800, C_ = 800, A_ = 128, HD_ = 8;
constexpr int F_ = 870;
constexpr int KX_ = IN_ + C_;          // 864
constexpr int KO_ = HD_ * F_;          // 6960
constexpr double RAD_ = 8.0, BOND_ = 3.8;
constexpr int NB = 256, NT = 512;

// ---- barrier state: first 1024 floats (4 KB) of ws ----
// arrival counters: cnt[32 + grp*32], grp=0..7 (distinct 128B lines)
// release flags  : cnt[288 + grp*32]
// ---- float region of ws (weights transposed + res f32) ----
constexpr size_t OF_RES = 1024;                                 // res [B][L][H] f32
constexpr size_t OF_WIT = OF_RES + (size_t)B_ * L_ * H_;        // W_ih^T [2400][864]
constexpr size_t OF_WHT = OF_WIT + (size_t)3 * H_ * KX_;        // W_hh^T [2400][800]
constexpr size_t OF_WOT = OF_WHT + (size_t)3 * H_ * H_;         // Wout^T [800][6960]
constexpr size_t FLT_END = OF_WOT + (size_t)C_ * KO_;           // even
// ---- double region ----
constexpr size_t D_ST  = 0;                                     // state dbuf [2][B][H]
constexpr size_t D_CTX = D_ST + 2ull * B_ * H_;                 // context [B][C]
constexpr size_t D_ANG = D_CTX + (size_t)B_ * C_;               // angles [B][L][3]
constexpr size_t D_POS = D_ANG + (size_t)B_ * L_ * 3;           // positions [B][L][3][3]
constexpr size_t D_DST = D_POS + (size_t)B_ * L_ * 9;           // dist [2][B][L][3] parity dbuf
constexpr size_t D_G   = D_DST + 2ull * B_ * L_ * 3;            // G [B][L][A]
constexpr size_t D_W   = D_G + (size_t)B_ * L_ * A_;            // w [B][L][HD]
constexpr size_t D_PN  = D_W + (size_t)B_ * L_ * HD_;           // pooledN [B][KO]
constexpr size_t D_END = D_PN + (size_t)B_ * KO_;
constexpr size_t WS_BYTES = FLT_END * 4 + D_END * 8;            // ~43.5 MB

// LDS geometry (floats). Type-A (bid<160): 5 neurons + 2 Wout cols.
// Type-B (bid>=160): 5 Wout cols.
constexpr int LD_NEUR = 4992;          // per-neuron: 3*864 ih + 3*800 hh
constexpr int LD_WOUT_A = 24960;       // type-A Wout base (5*4992)
constexpr int LD_TOT = 38880;          // 155,520 B

// Two-level grid barrier: 8 arrival lines (un-polled by waiters) + 8 release
// flag lines. Block 0 aggregates. Counters zeroed via hipMemsetAsync per launch.
__device__ __forceinline__ void gbar(unsigned* cnt, unsigned& ep) {
  ++ep;
  __syncthreads();
  const unsigned grp = (unsigned)blockIdx.x >> 5;               // 0..7, 32 blocks each
  if (threadIdx.x == 0)
    __hip_atomic_fetch_add(&cnt[32 + grp * 32], 1u,
                           __ATOMIC_RELEASE, __HIP_MEMORY_SCOPE_AGENT);
  if (blockIdx.x == 0) {
    if (threadIdx.x < 8) {
      while (__hip_atomic_load(&cnt[32 + threadIdx.x * 32],
                               __ATOMIC_ACQUIRE, __HIP_MEMORY_SCOPE_AGENT) < ep * 32u)
        __builtin_amdgcn_s_sleep(2);
    }
    __syncthreads();                                            // all 8 counters full
    if (threadIdx.x < 8)
      __hip_atomic_store(&cnt[288 + threadIdx.x * 32], ep,
                         __ATOMIC_RELEASE, __HIP_MEMORY_SCOPE_AGENT);
    __syncthreads();
  } else {
    if (threadIdx.x == 0) {
      while (__hip_atomic_load(&cnt[288 + grp * 32],
                               __ATOMIC_ACQUIRE, __HIP_MEMORY_SCOPE_AGENT) < ep)
        __builtin_amdgcn_s_sleep(4);
    }
    __syncthreads();
  }
}

__device__ void transp(const float* __restrict__ src, float* __restrict__ dst,
                       int R, int Cn, float* sm) {
  const int tr_ = (R + 31) >> 5, tc_ = (Cn + 31) >> 5;
  for (int t = blockIdx.x; t < tr_ * tc_; t += gridDim.x) {
    const int r0 = (t / tc_) << 5, c0 = (t % tc_) << 5;
    __syncthreads();
    for (int e = threadIdx.x; e < 1024; e += NT) {
      const int rr = e >> 5, cc = e & 31, r = r0 + rr, c = c0 + cc;
      sm[rr * 33 + cc] = (r < R && c < Cn) ? src[(size_t)r * Cn + c] : 0.0f;
    }
    __syncthreads();
    for (int e = threadIdx.x; e < 1024; e += NT) {
      const int cc = e >> 5, rr = e & 31, r = r0 + rr, c = c0 + cc;
      if (r < R && c < Cn) dst[(size_t)c * R + r] = sm[rr * 33 + cc];
    }
  }
}

} // namespace

extern "C" __global__ __launch_bounds__(NT, 1)
void srnn(const float* __restrict__ data, const float* __restrict__ W_ih,
          const float* __restrict__ W_hh, const float* __restrict__ b_ih,
          const float* __restrict__ b_hh, const float* __restrict__ Wa,
          const float* __restrict__ ba, const float* __restrict__ W1,
          const float* __restrict__ b1, const float* __restrict__ W2,
          const float* __restrict__ Wout, const float* __restrict__ bout,
          float* __restrict__ out, float* __restrict__ ws)
{
  __shared__ __align__(16) float wlds[LD_TOT];   // 155,520 B persistent weights
  __shared__ double smd[528];                    // 4,224 B scratch (1056 floats)
  float* smf = (float*)smd;
  unsigned* cnt = (unsigned*)ws;
  float* res   = ws + OF_RES;
  float* WihT  = ws + OF_WIT;
  float* WhhT  = ws + OF_WHT;
  float* WoutT = ws + OF_WOT;
  double* wd   = (double*)(ws + FLT_END);
  double* st2  = wd + D_ST;
  double* ctxD = wd + D_CTX;
  double* angD = wd + D_ANG;
  double* posD = wd + D_POS;
  double* dstD = wd + D_DST;                     // [2][B][L][3]
  double* Gd   = wd + D_G;
  double* wAr  = wd + D_W;
  double* pND  = wd + D_PN;

  const int bid = blockIdx.x, tid = threadIdx.x;
  const int wid = tid >> 6, lane = tid & 63;
  unsigned ep = 0;

  // ================= init =================
  for (int i = bid * NT + tid; i < (int)(D_ANG - D_ST); i += NB * NT)
    wd[i] = 0.0;
  {
    const int i = bid * NT + tid;                // B*L*A == NB*NT
    const int a = i & (A_ - 1);
    const int bj = i >> 7;
    double acc = (double)b1[a];
    const float* dr = data + (size_t)bj * IN_;
    #pragma unroll 8
    for (int k = 0; k < IN_; ++k)
      acc = fma((double)dr[k], (double)W1[(size_t)(H_ + k) * A_ + a], acc);
    Gd[i] = acc;
  }
  transp(W_ih, WihT, KX_, 3 * H_, smf);
  transp(W_hh, WhhT, H_, 3 * H_, smf);
  transp(Wout, WoutT, KO_, C_, smf);
  gbar(cnt, ep);

  // ---- load persistent LDS weight slices (coalesced, from transposed) ----
  if (bid < 160) {
    for (int rg = 0; rg < 15; ++rg) {            // ih rows: 5 neurons x 3 gates
      const int s = rg / 3, g = rg % 3;
      const int i = bid * 5 + s;
      const float4* src = reinterpret_cast<const float4*>(WihT + (size_t)(g * H_ + i) * KX_);
      float4* dst = reinterpret_cast<float4*>(&wlds[s * LD_NEUR + g * 864]);
      for (int k4 = tid; k4 < 216; k4 += NT) dst[k4] = src[k4];
    }
    for (int rg = 0; rg < 15; ++rg) {            // hh rows
      const int s = rg / 3, g = rg % 3;
      const int i = bid * 5 + s;
      const float4* src = reinterpret_cast<const float4*>(WhhT + (size_t)(g * H_ + i) * H_);
      float4* dst = reinterpret_cast<float4*>(&wlds[s * LD_NEUR + 2592 + g * 800]);
      for (int k4 = tid; k4 < 200; k4 += NT) dst[k4] = src[k4];
    }
    for (int cs = 0; cs < 2; ++cs) {             // 2 Wout cols
      const int c = bid * 2 + cs;
      const float4* src = reinterpret_cast<const float4*>(WoutT + (size_t)c * KO_);
      float4* dst = reinterpret_cast<float4*>(&wlds[LD_WOUT_A + cs * KO_]);
      for (int k4 = tid; k4 < 1740; k4 += NT) dst[k4] = src[k4];
    }
  } else {
    for (int cs = 0; cs < 5; ++cs) {             // 5 Wout cols
      const int c = 320 + (bid - 160) * 5 + cs;
      const float4* src = reinterpret_cast<const float4*>(WoutT + (size_t)c * KO_);
      float4* dst = reinterpret_cast<float4*>(&wlds[cs * KO_]);
      for (int k4 = tid; k4 < 1740; k4 += NT) dst[k4] = src[k4];
    }
  }
  __syncthreads();

  // ================= 128 steps, 3 barriers each =================
  for (int idx = 0; idx < L_; ++idx) {
    const int rp = idx & 1;
    const double* sOld = st2 + (size_t)rp * B_ * H_;
    double* sNew = st2 + (size_t)(rp ^ 1) * B_ * H_;
    const double* dstR = dstD + (size_t)(idx & 1) * (B_ * L_ * 3);       // read buf
    double* dstW = dstD + (size_t)((idx + 1) & 1) * (B_ * L_ * 3);       // write buf

    // ---- P1: GRU (type-A waves 0..4) || e/logits/w (remaining 1024 waves) ----
    if (bid < 160 && wid < 5) {
      const int i = bid * 5 + wid;               // neuron
      const int b = lane >> 3, ks = lane & 7;
      const float4* wr4 = reinterpret_cast<const float4*>(&wlds[wid * LD_NEUR]);
      const float4* wz4 = reinterpret_cast<const float4*>(&wlds[wid * LD_NEUR + 864]);
      const float4* wn4 = reinterpret_cast<const float4*>(&wlds[wid * LD_NEUR + 1728]);
      const float4* dx4 = reinterpret_cast<const float4*>(data + ((size_t)b * L_ + idx) * IN_);
      const double* cx = ctxD + (size_t)b * C_;
      double axr = 0., axz = 0., axn = 0.;
      #pragma unroll
      for (int j = 0; j < 2; ++j) {
        const int q = ks + 8 * j;
        const float4 x4 = dx4[q];
        const float4 r4 = wr4[q], z4 = wz4[q], n4 = wn4[q];
        const double x0 = x4.x, x1 = x4.y, x2 = x4.z, x3 = x4.w;
        axr = fma((double)r4.x, x0, axr); axr = fma((double)r4.y, x1, axr);
        axr = fma((double)r4.z, x2, axr); axr = fma((double)r4.w, x3, axr);
        axz = fma((double)z4.x, x0, axz); axz = fma((double)z4.y, x1, axz);
        axz = fma((double)z4.z, x2, axz); axz = fma((double)z4.w, x3, axz);
        axn = fma((double)n4.x, x0, axn); axn = fma((double)n4.y, x1, axn);
        axn = fma((double)n4.z, x2, axn); axn = fma((double)n4.w, x3, axn);
      }
      for (int j = 2; j < 27; ++j) {
        const int q = ks + 8 * j;
        const int e = 4 * q - 64;
        const double x0 = cx[e], x1 = cx[e + 1], x2 = cx[e + 2], x3 = cx[e + 3];
        const float4 r4 = wr4[q], z4 = wz4[q], n4 = wn4[q];
        axr = fma((double)r4.x, x0, axr); axr = fma((double)r4.y, x1, axr);
        axr = fma((double)r4.z, x2, axr); axr = fma((double)r4.w, x3, axr);
        axz = fma((double)z4.x, x0, axz); axz = fma((double)z4.y, x1, axz);
        axz = fma((double)z4.z, x2, axz); axz = fma((double)z4.w, x3, axz);
        axn = fma((double)n4.x, x0, axn); axn = fma((double)n4.y, x1, axn);
        axn = fma((double)n4.z, x2, axn); axn = fma((double)n4.w, x3, axn);
      }
      const float4* hr4 = reinterpret_cast<const float4*>(&wlds[wid * LD_NEUR + 2592]);
      const float4* hz4 = reinterpret_cast<const float4*>(&wlds[wid * LD_NEUR + 2592 + 800]);
      const float4* hn4 = reinterpret_cast<const float4*>(&wlds[wid * LD_NEUR + 2592 + 1600]);
      const double* sx = sOld + (size_t)b * H_;
      double ahr = 0., ahz = 0., ahn = 0.;
      for (int j = 0; j < 25; ++j) {
        const int q = ks + 8 * j;
        const int e = 4 * q;
        const double s0 = sx[e], s1 = sx[e + 1], s2 = sx[e + 2], s3 = sx[e + 3];
        const float4 r4 = hr4[q], z4 = hz4[q], n4 = hn4[q];
        ahr = fma((double)r4.x, s0, ahr); ahr = fma((double)r4.y, s1, ahr);
        ahr = fma((double)r4.z, s2, ahr); ahr = fma((double)r4.w, s3, ahr);
        ahz = fma((double)z4.x, s0, ahz); ahz = fma((double)z4.y, s1, ahz);
        ahz = fma((double)z4.z, s2, ahz); ahz = fma((double)z4.w, s3, ahz);
        ahn = fma((double)n4.x, s0, ahn); ahn = fma((double)n4.y, s1, ahn);
        ahn = fma((double)n4.z, s2, ahn); ahn = fma((double)n4.w, s3, ahn);
      }
      #pragma unroll
      for (int off = 1; off < 8; off <<= 1) {
        axr += __shfl_xor(axr, off); axz += __shfl_xor(axz, off); axn += __shfl_xor(axn, off);
        ahr += __shfl_xor(ahr, off); ahz += __shfl_xor(ahz, off); ahn += __shfl_xor(ahn, off);
      }
      if (ks == 0) {
        const double xr = axr + (double)b_ih[i], xz = axz + (double)b_ih[H_ + i],
                     xn = axn + (double)b_ih[2 * H_ + i];
        const double hr = ahr + (double)b_hh[i], hz = ahz + (double)b_hh[H_ + i],
                     hn = ahn + (double)b_hh[2 * H_ + i];
        const double r = 1.0 / (1.0 + exp(-(xr + hr)));
        const double z = 1.0 / (1.0 + exp(-(xz + hz)));
        const double n = tanh(xn + r * hn);
        const double sn = (1.0 - z) * n + z * sOld[b * H_ + i];
        sNew[b * H_ + i] = sn;
        res[((size_t)b * L_ + idx) * H_ + i] = (float)sn;
      }
    } else {
      int tsk = -1;
      if (bid >= 160) tsk = (bid - 160) * 8 + wid;          // 0..767
      else tsk = 768 + bid * 3 + (wid - 5);                  // 768..1247
      if (tsk < 1024 && idx > 0) {
        const int b = tsk >> 7, j = tsk & (L_ - 1);
        const size_t bj = (size_t)b * L_ + j;
        double e0 = Gd[bj * A_ + lane], e1 = Gd[bj * A_ + lane + 64];
        const double an0 = angD[bj * 3], an1 = angD[bj * 3 + 1], an2 = angD[bj * 3 + 2];
        const double dd0 = dstR[bj * 3], dd1 = dstR[bj * 3 + 1], dd2 = dstR[bj * 3 + 2];
        e0 = fma((double)W1[864 * A_ + lane], an0, e0);
        e0 = fma((double)W1[865 * A_ + lane], an1, e0);
        e0 = fma((double)W1[866 * A_ + lane], an2, e0);
        e0 = fma((double)W1[867 * A_ + lane], dd0, e0);
        e0 = fma((double)W1[868 * A_ + lane], dd1, e0);
        e0 = fma((double)W1[869 * A_ + lane], dd2, e0);
        e1 = fma((double)W1[864 * A_ + lane + 64], an0, e1);
        e1 = fma((double)W1[865 * A_ + lane + 64], an1, e1);
        e1 = fma((double)W1[866 * A_ + lane + 64], an2, e1);
        e1 = fma((double)W1[867 * A_ + lane + 64], dd0, e1);
        e1 = fma((double)W1[868 * A_ + lane + 64], dd1, e1);
        e1 = fma((double)W1[869 * A_ + lane + 64], dd2, e1);
        e0 = tanh(e0); e1 = tanh(e1);
        double lg[8];
        #pragma unroll
        for (int h = 0; h < 8; ++h) {
          double v = fma(e0, (double)W2[lane * 8 + h], e1 * (double)W2[(lane + 64) * 8 + h]);
          #pragma unroll
          for (int off = 1; off < 64; off <<= 1) v += __shfl_xor(v, off);
          lg[h] = v;
        }
        if (lane == 0) {
          const bool valid = (j < idx) && (dd1 <= RAD_);
          double* wrow = wAr + bj * HD_;
          #pragma unroll
          for (int h = 0; h < 8; ++h) wrow[h] = valid ? exp(lg[h]) : 0.0;
        }
      }
    }
    gbar(cnt, ep);

    // ---- P2: pooled (0..127) || G-update (128..135) || angle+pos+dist (136) ----
    if (bid < 128) {
      if (idx > 0) {                             // per (b, f-slice of 55), all 8 heads
        const int b = bid >> 4, sl = bid & 15;
        const int f0 = sl * 55;
        const int fn = (F_ - f0 < 55) ? (F_ - f0) : 55;
        const int fl = tid >> 3, h = tid & 7;
        if (fl < fn) {
          const int f = f0 + fl;
          const float* fbf = nullptr; const double* fbd = nullptr; int strd = 0;
          if (f < H_)                { fbf = res  + f + (size_t)b * L_ * H_;               strd = H_;  }
          else if (f < H_ + IN_)     { fbf = data + (f - H_) + (size_t)b * L_ * IN_;       strd = IN_; }
          else if (f < H_ + IN_ + 3) { fbd = angD + (f - H_ - IN_) + (size_t)b * L_ * 3;   strd = 3;   }
          else                       { fbd = dstR + (f - H_ - IN_ - 3) + (size_t)b * L_ * 3; strd = 3; }
          const double* wp = wAr + (size_t)b * L_ * HD_ + h;
          double acc = 0.0, zs = 0.0;
          for (int j = 0; j < idx; ++j) {
            const double wj = wp[(size_t)j * HD_];
            zs += wj;
            const double fv = fbf ? (double)fbf[(size_t)j * strd] : fbd[(size_t)j * strd];
            acc = fma(wj, fv, acc);
          }
          pND[(size_t)b * KO_ + (size_t)h * F_ + f] = acc / zs;
        }
      }
    } else if (bid < 136) {
      const int b = bid - 128;                   // G-row update for step idx
      const int a = tid & (A_ - 1), ksl = tid >> 7;
      const double* sr = sNew + (size_t)b * H_;
      const int i0 = ksl * 200;
      double p = 0.0;
      for (int k = 0; k < 200; ++k)
        p = fma(sr[i0 + k], (double)W1[(size_t)(i0 + k) * A_ + a], p);
      smd[tid] = p;
      __syncthreads();
      if (tid < 128)
        Gd[((size_t)b * L_ + idx) * A_ + tid] +=
            smd[tid] + smd[128 + tid] + smd[256 + tid] + smd[384 + tid];
    } else if (bid == 136) {
      // angle = state@Wa+ba; positions row idx; outputs; then dist (write parity buf)
      const int b7 = tid / 48, rem = tid % 48, t3 = rem / 16, ksl = rem & 15;
      if (tid < 384) {
        const double* sr = sNew + (size_t)b7 * H_;
        const int i0 = ksl * 50;
        double p = 0.0;
        for (int k = 0; k < 50; ++k)
          p = fma(sr[i0 + k], (double)Wa[(i0 + k) * 3 + t3], p);
        smd[tid] = p;
      }
      __syncthreads();
      if (tid < 24) {
        const int b2 = tid / 3, t4 = tid % 3;
        double s = (double)ba[t4];
        for (int u = 0; u < 16; ++u) s += smd[b2 * 48 + t4 * 16 + u];
        smd[384 + tid] = s;
        angD[((size_t)b2 * L_ + idx) * 3 + t4] = s;
        out[(size_t)B_ * L_ * 9 + ((size_t)b2 * L_ + idx) * 3 + t4] = (float)s;
      }
      __syncthreads();
      if (tid < 24) {
        const int b2 = tid / 3, t4 = tid % 3;
        const double a = smd[384 + b2 * 3 + t4];
        const double asum = smd[384 + b2 * 3] + smd[384 + b2 * 3 + 1] + smd[384 + b2 * 3 + 2];
        const double sa = sin(a), ca = cos(a), cs = cos(asum), ss = sin(asum);
        double px = 0., py = 0., pz = 0.;
        if (idx > 0) {
          const double* pr = posD + ((size_t)b2 * L_ + idx - 1) * 9 + t4 * 3;
          px = pr[0]; py = pr[1]; pz = pr[2];
        }
        px = fma(BOND_, ca, px);
        py = fma(BOND_, sa * cs, py);
        pz = fma(BOND_, sa * ss, pz);
        double* pw = posD + ((size_t)b2 * L_ + idx) * 9 + t4 * 3;
        pw[0] = px; pw[1] = py; pw[2] = pz;
        float* ow = out + ((size_t)b2 * L_ + idx) * 9 + t4 * 3;
        ow[0] = (float)px; ow[1] = (float)py; ow[2] = (float)pz;
      }
      __syncthreads();
      if (idx < L_ - 1) {                        // dist rows j<=idx vs positions[idx]
        for (int u = tid; u < 4096; u += NT) {
          const int b = u >> 9, rem2 = u & 511;
          const int j = rem2 >> 2, t6 = rem2 & 3;
          if (t6 < 3 && j <= idx) {
            const double* pa = posD + ((size_t)b * L_ + idx) * 9 + t6 * 3;
            const double* pb = posD + ((size_t)b * L_ + j) * 9 + t6 * 3;
            const double dx = pa[0] - pb[0], dy = pa[1] - pb[1], dz = pa[2] - pb[2];
            dstW[((size_t)b * L_ + j) * 3 + t6] =
                sqrt(fma(dx, dx, fma(dy, dy, fma(dz, dz, 1e-12))));
          }
        }
      }
    }
    gbar(cnt, ep);

    // ---- P3: ctx = pooledN @ Wout(LDS cols) + bout ----
    if (idx < L_ - 1) {
      const int ntask = (bid < 160) ? 2 : 5;     // tasks per wave = cols per block
      for (int u = 0; u < ntask; ++u) {
        const int t = wid + 8 * u;
        const int cs = t >> 3, b = t & 7;
        const int c = (bid < 160) ? (bid * 2 + cs) : (320 + (bid - 160) * 5 + cs);
        const int cbase = ((bid < 160) ? LD_WOUT_A : 0) + cs * KO_;
        double acc = 0.0;
        if (idx > 0) {
          const double* pr = pND + (size_t)b * KO_;
          for (int m = 0; m < 28; ++m) {
            const int q = lane + 64 * m;
            if (q < 1740) {
              const float4 w4 = *reinterpret_cast<const float4*>(&wlds[cbase + 4 * q]);
              const int e = 4 * q;
              acc = fma((double)w4.x, pr[e],     acc);
              acc = fma((double)w4.y, pr[e + 1], acc);
              acc = fma((double)w4.z, pr[e + 2], acc);
              acc = fma((double)w4.w, pr[e + 3], acc);
            }
          }
          #pragma unroll
          for (int off = 1; off < 64; off <<= 1) acc += __shfl_xor(acc, off);
        }
        if (lane == 0)
          ctxD[b * C_ + c] = (idx > 0) ? (acc + (double)bout[c]) : 0.0;
      }
    }
    gbar(cnt, ep);
  }
}

extern "C" void kernel_launch(void* const* d_in, const int* in_sizes, int n_in,
                              void* d_out, int out_size, void* d_ws, size_t ws_size,
                              hipStream_t stream) {
  (void)in_sizes; (void)n_in; (void)out_size;
  if (ws_size < WS_BYTES) return;
  const float* data = (const float*)d_in[0];
  const float* W_ih = (const float*)d_in[1];
  const float* W_hh = (const float*)d_in[2];
  const float* b_ih = (const float*)d_in[3];
  const float* b_hh = (const float*)d_in[4];
  const float* Wa   = (const float*)d_in[5];
  const float* ba   = (const float*)d_in[6];
  const float* W1   = (const float*)d_in[7];
  const float* b1   = (const float*)d_in[8];
  const float* W2   = (const float*)d_in[9];
  const float* Wout = (const float*)d_in[10];
  const float* bout = (const float*)d_in[11];
  hipMemsetAsync(d_ws, 0, 4096, stream);         // reset barrier state (replay-safe)
  srnn<<<dim3(NB), dim3(NT), 0, stream>>>(data, W_ih, W_hh, b_ih, b_hh, Wa, ba,
                                          W1, b1, W2, Wout, bout,
                                          (float*)d_out, (float*)d_ws);
}

// Round 6
// 12712.988 us; speedup vs baseline: 4.4786x; 4.4786x over previous
//
#include <hip/hip_runtime.h>
#include <cmath>

namespace {

constexpr int B_ = 8, L_ = 128, IN_ = 64, H_ = 800, C_ = 800, A_ = 128, HD_ = 8;
constexpr int F_ = 870;
constexpr int KX_ = IN_ + C_;          // 864
constexpr int KO_ = HD_ * F_;          // 6960
constexpr double RAD_ = 8.0, BOND_ = 3.8;
constexpr int NB = 256, NT = 512;

// ---- barrier state: first 1024 floats (4 KB) of ws ----
// arrival counters: cnt[32 + grp*32], grp=0..7 (distinct 128B lines)
// release flags  : cnt[288 + grp*32]
// ---- float region of ws (weights transposed + res f32) ----
constexpr size_t OF_RES = 1024;                                 // res [B][L][H] f32
constexpr size_t OF_WIT = OF_RES + (size_t)B_ * L_ * H_;        // W_ih^T [2400][864]
constexpr size_t OF_WHT = OF_WIT + (size_t)3 * H_ * KX_;        // W_hh^T [2400][800]
constexpr size_t OF_WOT = OF_WHT + (size_t)3 * H_ * H_;         // Wout^T [800][6960]
constexpr size_t FLT_END = OF_WOT + (size_t)C_ * KO_;           // even
// ---- double region ----
constexpr size_t D_ST  = 0;                                     // state dbuf [2][B][H]
constexpr size_t D_CTX = D_ST + 2ull * B_ * H_;                 // context [B][C]
constexpr size_t D_ANG = D_CTX + (size_t)B_ * C_;               // angles [B][L][3]
constexpr size_t D_POS = D_ANG + (size_t)B_ * L_ * 3;           // positions [B][L][3][3]
constexpr size_t D_DST = D_POS + (size_t)B_ * L_ * 9;           // dist [2][B][L][3] parity dbuf
constexpr size_t D_G   = D_DST + 2ull * B_ * L_ * 3;            // G [B][L][A]
constexpr size_t D_W   = D_G + (size_t)B_ * L_ * A_;            // w [B][L][HD]
constexpr size_t D_PN  = D_W + (size_t)B_ * L_ * HD_;           // pooledN [B][KO]
constexpr size_t D_END = D_PN + (size_t)B_ * KO_;
constexpr size_t WS_BYTES = FLT_END * 4 + D_END * 8;            // ~43.5 MB

// LDS geometry (floats). Type-A (bid<160): 5 neurons + 2 Wout cols.
// Type-B (bid>=160): 5 Wout cols.
constexpr int LD_NEUR = 4992;          // per-neuron: 3*864 ih + 3*800 hh
constexpr int LD_WOUT_A = 24960;       // type-A Wout base (5*4992)
constexpr int LD_TOT = 38880;          // 155,520 B

// Two-level grid barrier, minimal-fence version.
// - arrival: fetch_add(RELEASE) = exactly one buffer_wbl2 per block (pushes this
//   block's ordinary stores, already drained into L2 by __syncthreads, to the
//   coherent point).
// - all polling is RELAXED (no buffer_inv per iteration -- this was the round-5
//   killer: acquire-polls invalidate the whole XCD L2 every ~250ns).
// - after flag observed: ONE fence(ACQUIRE,"agent") by thread 0 (one buffer_inv
//   per block; block occupies a single CU so one inv covers all its lanes),
//   then __syncthreads orders the rest of the block behind it.
__device__ __forceinline__ void gbar(unsigned* cnt, unsigned& ep) {
  ++ep;
  __syncthreads();
  const unsigned grp = (unsigned)blockIdx.x >> 5;               // 0..7, 32 blocks each
  if (threadIdx.x == 0)
    __hip_atomic_fetch_add(&cnt[32 + grp * 32], 1u,
                           __ATOMIC_RELEASE, __HIP_MEMORY_SCOPE_AGENT);
  if (blockIdx.x == 0) {
    if (threadIdx.x < 8) {
      const unsigned tgt = ep * 32u;
      while (__hip_atomic_load(&cnt[32 + threadIdx.x * 32],
                               __ATOMIC_RELAXED, __HIP_MEMORY_SCOPE_AGENT) < tgt)
        __builtin_amdgcn_s_sleep(1);
    }
    if (threadIdx.x == 0)
      __builtin_amdgcn_fence(__ATOMIC_ACQUIRE, "agent");
    __syncthreads();                                            // all 8 counters full
    if (threadIdx.x < 8)
      __hip_atomic_store(&cnt[288 + threadIdx.x * 32], ep,
                         __ATOMIC_RELEASE, __HIP_MEMORY_SCOPE_AGENT);
    __syncthreads();
  } else {
    if (threadIdx.x == 0) {
      while (__hip_atomic_load(&cnt[288 + grp * 32],
                               __ATOMIC_RELAXED, __HIP_MEMORY_SCOPE_AGENT) < ep)
        __builtin_amdgcn_s_sleep(1);
      __builtin_amdgcn_fence(__ATOMIC_ACQUIRE, "agent");
    }
    __syncthreads();
  }
}

__device__ void transp(const float* __restrict__ src, float* __restrict__ dst,
                       int R, int Cn, float* sm) {
  const int tr_ = (R + 31) >> 5, tc_ = (Cn + 31) >> 5;
  for (int t = blockIdx.x; t < tr_ * tc_; t += gridDim.x) {
    const int r0 = (t / tc_) << 5, c0 = (t % tc_) << 5;
    __syncthreads();
    for (int e = threadIdx.x; e < 1024; e += NT) {
      const int rr = e >> 5, cc = e & 31, r = r0 + rr, c = c0 + cc;
      sm[rr * 33 + cc] = (r < R && c < Cn) ? src[(size_t)r * Cn + c] : 0.0f;
    }
    __syncthreads();
    for (int e = threadIdx.x; e < 1024; e += NT) {
      const int cc = e >> 5, rr = e & 5 * 0 + (e & 31), r = r0 + (e & 31), c = c0 + (e >> 5);
      (void)rr;
      if (r < R && c < Cn) dst[(size_t)c * R + r] = sm[(e & 31) * 33 + (e >> 5)];
    }
  }
}

} // namespace

extern "C" __global__ __launch_bounds__(NT, 1)
void srnn(const float* __restrict__ data, const float* __restrict__ W_ih,
          const float* __restrict__ W_hh, const float* __restrict__ b_ih,
          const float* __restrict__ b_hh, const float* __restrict__ Wa,
          const float* __restrict__ ba, const float* __restrict__ W1,
          const float* __restrict__ b1, const float* __restrict__ W2,
          const float* __restrict__ Wout, const float* __restrict__ bout,
          float* __restrict__ out, float* __restrict__ ws)
{
  __shared__ __align__(16) float wlds[LD_TOT];   // 155,520 B persistent weights
  __shared__ double smd[528];                    // 4,224 B scratch (1056 floats)
  float* smf = (float*)smd;
  unsigned* cnt = (unsigned*)ws;
  float* res   = ws + OF_RES;
  float* WihT  = ws + OF_WIT;
  float* WhhT  = ws + OF_WHT;
  float* WoutT = ws + OF_WOT;
  double* wd   = (double*)(ws + FLT_END);
  double* st2  = wd + D_ST;
  double* ctxD = wd + D_CTX;
  double* angD = wd + D_ANG;
  double* posD = wd + D_POS;
  double* dstD = wd + D_DST;                     // [2][B][L][3]
  double* Gd   = wd + D_G;
  double* wAr  = wd + D_W;
  double* pND  = wd + D_PN;

  const int bid = blockIdx.x, tid = threadIdx.x;
  const int wid = tid >> 6, lane = tid & 63;
  unsigned ep = 0;

  // ================= init =================
  for (int i = bid * NT + tid; i < (int)(D_ANG - D_ST); i += NB * NT)
    wd[i] = 0.0;
  {
    const int i = bid * NT + tid;                // B*L*A == NB*NT
    const int a = i & (A_ - 1);
    const int bj = i >> 7;
    double acc = (double)b1[a];
    const float* dr = data + (size_t)bj * IN_;
    #pragma unroll 8
    for (int k = 0; k < IN_; ++k)
      acc = fma((double)dr[k], (double)W1[(size_t)(H_ + k) * A_ + a], acc);
    Gd[i] = acc;
  }
  transp(W_ih, WihT, KX_, 3 * H_, smf);
  transp(W_hh, WhhT, H_, 3 * H_, smf);
  transp(Wout, WoutT, KO_, C_, smf);
  gbar(cnt, ep);

  // ---- load persistent LDS weight slices (coalesced, from transposed) ----
  if (bid < 160) {
    for (int rg = 0; rg < 15; ++rg) {            // ih rows: 5 neurons x 3 gates
      const int s = rg / 3, g = rg % 3;
      const int i = bid * 5 + s;
      const float4* src = reinterpret_cast<const float4*>(WihT + (size_t)(g * H_ + i) * KX_);
      float4* dst = reinterpret_cast<float4*>(&wlds[s * LD_NEUR + g * 864]);
      for (int k4 = tid; k4 < 216; k4 += NT) dst[k4] = src[k4];
    }
    for (int rg = 0; rg < 15; ++rg) {            // hh rows
      const int s = rg / 3, g = rg % 3;
      const int i = bid * 5 + s;
      const float4* src = reinterpret_cast<const float4*>(WhhT + (size_t)(g * H_ + i) * H_);
      float4* dst = reinterpret_cast<float4*>(&wlds[s * LD_NEUR + 2592 + g * 800]);
      for (int k4 = tid; k4 < 200; k4 += NT) dst[k4] = src[k4];
    }
    for (int cs = 0; cs < 2; ++cs) {             // 2 Wout cols
      const int c = bid * 2 + cs;
      const float4* src = reinterpret_cast<const float4*>(WoutT + (size_t)c * KO_);
      float4* dst = reinterpret_cast<float4*>(&wlds[LD_WOUT_A + cs * KO_]);
      for (int k4 = tid; k4 < 1740; k4 += NT) dst[k4] = src[k4];
    }
  } else {
    for (int cs = 0; cs < 5; ++cs) {             // 5 Wout cols
      const int c = 320 + (bid - 160) * 5 + cs;
      const float4* src = reinterpret_cast<const float4*>(WoutT + (size_t)c * KO_);
      float4* dst = reinterpret_cast<float4*>(&wlds[cs * KO_]);
      for (int k4 = tid; k4 < 1740; k4 += NT) dst[k4] = src[k4];
    }
  }
  __syncthreads();

  // ================= 128 steps, 3 barriers each =================
  for (int idx = 0; idx < L_; ++idx) {
    const int rp = idx & 1;
    const double* sOld = st2 + (size_t)rp * B_ * H_;
    double* sNew = st2 + (size_t)(rp ^ 1) * B_ * H_;
    const double* dstR = dstD + (size_t)(idx & 1) * (B_ * L_ * 3);       // read buf
    double* dstW = dstD + (size_t)((idx + 1) & 1) * (B_ * L_ * 3);       // write buf

    // ---- P1: GRU (type-A waves 0..4) || e/logits/w (remaining 1024 waves) ----
    if (bid < 160 && wid < 5) {
      const int i = bid * 5 + wid;               // neuron
      const int b = lane >> 3, ks = lane & 7;
      const float4* wr4 = reinterpret_cast<const float4*>(&wlds[wid * LD_NEUR]);
      const float4* wz4 = reinterpret_cast<const float4*>(&wlds[wid * LD_NEUR + 864]);
      const float4* wn4 = reinterpret_cast<const float4*>(&wlds[wid * LD_NEUR + 1728]);
      const float4* dx4 = reinterpret_cast<const float4*>(data + ((size_t)b * L_ + idx) * IN_);
      const double* cx = ctxD + (size_t)b * C_;
      double axr = 0., axz = 0., axn = 0.;
      #pragma unroll
      for (int j = 0; j < 2; ++j) {
        const int q = ks + 8 * j;
        const float4 x4 = dx4[q];
        const float4 r4 = wr4[q], z4 = wz4[q], n4 = wn4[q];
        const double x0 = x4.x, x1 = x4.y, x2 = x4.z, x3 = x4.w;
        axr = fma((double)r4.x, x0, axr); axr = fma((double)r4.y, x1, axr);
        axr = fma((double)r4.z, x2, axr); axr = fma((double)r4.w, x3, axr);
        axz = fma((double)z4.x, x0, axz); axz = fma((double)z4.y, x1, axz);
        axz = fma((double)z4.z, x2, axz); axz = fma((double)z4.w, x3, axz);
        axn = fma((double)n4.x, x0, axn); axn = fma((double)n4.y, x1, axn);
        axn = fma((double)n4.z, x2, axn); axn = fma((double)n4.w, x3, axn);
      }
      for (int j = 2; j < 27; ++j) {
        const int q = ks + 8 * j;
        const int e = 4 * q - 64;
        const double x0 = cx[e], x1 = cx[e + 1], x2 = cx[e + 2], x3 = cx[e + 3];
        const float4 r4 = wr4[q], z4 = wz4[q], n4 = wn4[q];
        axr = fma((double)r4.x, x0, axr); axr = fma((double)r4.y, x1, axr);
        axr = fma((double)r4.z, x2, axr); axr = fma((double)r4.w, x3, axr);
        axz = fma((double)z4.x, x0, axz); axz = fma((double)z4.y, x1, axz);
        axz = fma((double)z4.z, x2, axz); axz = fma((double)z4.w, x3, axz);
        axn = fma((double)n4.x, x0, axn); axn = fma((double)n4.y, x1, axn);
        axn = fma((double)n4.z, x2, axn); axn = fma((double)n4.w, x3, axn);
      }
      const float4* hr4 = reinterpret_cast<const float4*>(&wlds[wid * LD_NEUR + 2592]);
      const float4* hz4 = reinterpret_cast<const float4*>(&wlds[wid * LD_NEUR + 2592 + 800]);
      const float4* hn4 = reinterpret_cast<const float4*>(&wlds[wid * LD_NEUR + 2592 + 1600]);
      const double* sx = sOld + (size_t)b * H_;
      double ahr = 0., ahz = 0., ahn = 0.;
      for (int j = 0; j < 25; ++j) {
        const int q = ks + 8 * j;
        const int e = 4 * q;
        const double s0 = sx[e], s1 = sx[e + 1], s2 = sx[e + 2], s3 = sx[e + 3];
        const float4 r4 = hr4[q], z4 = hz4[q], n4 = hn4[q];
        ahr = fma((double)r4.x, s0, ahr); ahr = fma((double)r4.y, s1, ahr);
        ahr = fma((double)r4.z, s2, ahr); ahr = fma((double)r4.w, s3, ahr);
        ahz = fma((double)z4.x, s0, ahz); ahz = fma((double)z4.y, s1, ahz);
        ahz = fma((double)z4.z, s2, ahz); ahz = fma((double)z4.w, s3, ahz);
        ahn = fma((double)n4.x, s0, ahn); ahn = fma((double)n4.y, s1, ahn);
        ahn = fma((double)n4.z, s2, ahn); ahn = fma((double)n4.w, s3, ahn);
      }
      #pragma unroll
      for (int off = 1; off < 8; off <<= 1) {
        axr += __shfl_xor(axr, off); axz += __shfl_xor(axz, off); axn += __shfl_xor(axn, off);
        ahr += __shfl_xor(ahr, off); ahz += __shfl_xor(ahz, off); ahn += __shfl_xor(ahn, off);
      }
      if (ks == 0) {
        const double xr = axr + (double)b_ih[i], xz = axz + (double)b_ih[H_ + i],
                     xn = axn + (double)b_ih[2 * H_ + i];
        const double hr = ahr + (double)b_hh[i], hz = ahz + (double)b_hh[H_ + i],
                     hn = ahn + (double)b_hh[2 * H_ + i];
        const double r = 1.0 / (1.0 + exp(-(xr + hr)));
        const double z = 1.0 / (1.0 + exp(-(xz + hz)));
        const double n = tanh(xn + r * hn);
        const double sn = (1.0 - z) * n + z * sOld[b * H_ + i];
        sNew[b * H_ + i] = sn;
        res[((size_t)b * L_ + idx) * H_ + i] = (float)sn;
      }
    } else {
      int tsk = -1;
      if (bid >= 160) tsk = (bid - 160) * 8 + wid;          // 0..767
      else tsk = 768 + bid * 3 + (wid - 5);                  // 768..1247
      if (tsk < 1024 && idx > 0) {
        const int b = tsk >> 7, j = tsk & (L_ - 1);
        const size_t bj = (size_t)b * L_ + j;
        double e0 = Gd[bj * A_ + lane], e1 = Gd[bj * A_ + lane + 64];
        const double an0 = angD[bj * 3], an1 = angD[bj * 3 + 1], an2 = angD[bj * 3 + 2];
        const double dd0 = dstR[bj * 3], dd1 = dstR[bj * 3 + 1], dd2 = dstR[bj * 3 + 2];
        e0 = fma((double)W1[864 * A_ + lane], an0, e0);
        e0 = fma((double)W1[865 * A_ + lane], an1, e0);
        e0 = fma((double)W1[866 * A_ + lane], an2, e0);
        e0 = fma((double)W1[867 * A_ + lane], dd0, e0);
        e0 = fma((double)W1[868 * A_ + lane], dd1, e0);
        e0 = fma((double)W1[869 * A_ + lane], dd2, e0);
        e1 = fma((double)W1[864 * A_ + lane + 64], an0, e1);
        e1 = fma((double)W1[865 * A_ + lane + 64], an1, e1);
        e1 = fma((double)W1[866 * A_ + lane + 64], an2, e1);
        e1 = fma((double)W1[867 * A_ + lane + 64], dd0, e1);
        e1 = fma((double)W1[868 * A_ + lane + 64], dd1, e1);
        e1 = fma((double)W1[869 * A_ + lane + 64], dd2, e1);
        e0 = tanh(e0); e1 = tanh(e1);
        double lg[8];
        #pragma unroll
        for (int h = 0; h < 8; ++h) {
          double v = fma(e0, (double)W2[lane * 8 + h], e1 * (double)W2[(lane + 64) * 8 + h]);
          #pragma unroll
          for (int off = 1; off < 64; off <<= 1) v += __shfl_xor(v, off);
          lg[h] = v;
        }
        if (lane == 0) {
          const bool valid = (j < idx) && (dd1 <= RAD_);
          double* wrow = wAr + bj * HD_;
          #pragma unroll
          for (int h = 0; h < 8; ++h) wrow[h] = valid ? exp(lg[h]) : 0.0;
        }
      }
    }
    gbar(cnt, ep);

    // ---- P2: pooled (0..127) || G-update (128..135) || angle+pos+dist (136) ----
    if (bid < 128) {
      if (idx > 0) {                             // per (b, f-slice of 55), all 8 heads
        const int b = bid >> 4, sl = bid & 15;
        const int f0 = sl * 55;
        const int fn = (F_ - f0 < 55) ? (F_ - f0) : 55;
        const int fl = tid >> 3, h = tid & 7;
        if (fl < fn) {
          const int f = f0 + fl;
          const float* fbf = nullptr; const double* fbd = nullptr; int strd = 0;
          if (f < H_)                { fbf = res  + f + (size_t)b * L_ * H_;               strd = H_;  }
          else if (f < H_ + IN_)     { fbf = data + (f - H_) + (size_t)b * L_ * IN_;       strd = IN_; }
          else if (f < H_ + IN_ + 3) { fbd = angD + (f - H_ - IN_) + (size_t)b * L_ * 3;   strd = 3;   }
          else                       { fbd = dstR + (f - H_ - IN_ - 3) + (size_t)b * L_ * 3; strd = 3; }
          const double* wp = wAr + (size_t)b * L_ * HD_ + h;
          double acc = 0.0, zs = 0.0;
          for (int j = 0; j < idx; ++j) {
            const double wj = wp[(size_t)j * HD_];
            zs += wj;
            const double fv = fbf ? (double)fbf[(size_t)j * strd] : fbd[(size_t)j * strd];
            acc = fma(wj, fv, acc);
          }
          pND[(size_t)b * KO_ + (size_t)h * F_ + f] = acc / zs;
        }
      }
    } else if (bid < 136) {
      const int b = bid - 128;                   // G-row update for step idx
      const int a = tid & (A_ - 1), ksl = tid >> 7;
      const double* sr = sNew + (size_t)b * H_;
      const int i0 = ksl * 200;
      double p = 0.0;
      for (int k = 0; k < 200; ++k)
        p = fma(sr[i0 + k], (double)W1[(size_t)(i0 + k) * A_ + a], p);
      smd[tid] = p;
      __syncthreads();
      if (tid < 128)
        Gd[((size_t)b * L_ + idx) * A_ + tid] +=
            smd[tid] + smd[128 + tid] + smd[256 + tid] + smd[384 + tid];
    } else if (bid == 136) {
      // angle = state@Wa+ba; positions row idx; outputs; then dist (write parity buf)
      const int b7 = tid / 48, rem = tid % 48, t3 = rem / 16, ksl = rem & 15;
      if (tid < 384) {
        const double* sr = sNew + (size_t)b7 * H_;
        const int i0 = ksl * 50;
        double p = 0.0;
        for (int k = 0; k < 50; ++k)
          p = fma(sr[i0 + k], (double)Wa[(i0 + k) * 3 + t3], p);
        smd[tid] = p;
      }
      __syncthreads();
      if (tid < 24) {
        const int b2 = tid / 3, t4 = tid % 3;
        double s = (double)ba[t4];
        for (int u = 0; u < 16; ++u) s += smd[b2 * 48 + t4 * 16 + u];
        smd[384 + tid] = s;
        angD[((size_t)b2 * L_ + idx) * 3 + t4] = s;
        out[(size_t)B_ * L_ * 9 + ((size_t)b2 * L_ + idx) * 3 + t4] = (float)s;
      }
      __syncthreads();
      if (tid < 24) {
        const int b2 = tid / 3, t4 = tid % 3;
        const double a = smd[384 + b2 * 3 + t4];
        const double asum = smd[384 + b2 * 3] + smd[384 + b2 * 3 + 1] + smd[384 + b2 * 3 + 2];
        const double sa = sin(a), ca = cos(a), cs = cos(asum), ss = sin(asum);
        double px = 0., py = 0., pz = 0.;
        if (idx > 0) {
          const double* pr = posD + ((size_t)b2 * L_ + idx - 1) * 9 + t4 * 3;
          px = pr[0]; py = pr[1]; pz = pr[2];
        }
        px = fma(BOND_, ca, px);
        py = fma(BOND_, sa * cs, py);
        pz = fma(BOND_, sa * ss, pz);
        double* pw = posD + ((size_t)b2 * L_ + idx) * 9 + t4 * 3;
        pw[0] = px; pw[1] = py; pw[2] = pz;
        float* ow = out + ((size_t)b2 * L_ + idx) * 9 + t4 * 3;
        ow[0] = (float)px; ow[1] = (float)py; ow[2] = (float)pz;
      }
      __syncthreads();
      if (idx < L_ - 1) {                        // dist rows j<=idx vs positions[idx]
        for (int u = tid; u < 4096; u += NT) {
          const int b = u >> 9, rem2 = u & 511;
          const int j = rem2 >> 2, t6 = rem2 & 3;
          if (t6 < 3 && j <= idx) {
            const double* pa = posD + ((size_t)b * L_ + idx) * 9 + t6 * 3;
            const double* pb = posD + ((size_t)b * L_ + j) * 9 + t6 * 3;
            const double dx = pa[0] - pb[0], dy = pa[1] - pb[1], dz = pa[2] - pb[2];
            dstW[((size_t)b * L_ + j) * 3 + t6] =
                sqrt(fma(dx, dx, fma(dy, dy, fma(dz, dz, 1e-12))));
          }
        }
      }
    }
    gbar(cnt, ep);

    // ---- P3: ctx = pooledN @ Wout(LDS cols) + bout ----
    if (idx < L_ - 1) {
      const int ntask = (bid < 160) ? 2 : 5;     // tasks per wave = cols per block
      for (int u = 0; u < ntask; ++u) {
        const int t = wid + 8 * u;
        const int cs = t >> 3, b = t & 7;
        const int c = (bid < 160) ? (bid * 2 + cs) : (320 + (bid - 160) * 5 + cs);
        const int cbase = ((bid < 160) ? LD_WOUT_A : 0) + cs * KO_;
        double acc = 0.0;
        if (idx > 0) {
          const double* pr = pND + (size_t)b * KO_;
          for (int m = 0; m < 28; ++m) {
            const int q = lane + 64 * m;
            if (q < 1740) {
              const float4 w4 = *reinterpret_cast<const float4*>(&wlds[cbase + 4 * q]);
              const int e = 4 * q;
              acc = fma((double)w4.x, pr[e],     acc);
              acc = fma((double)w4.y, pr[e + 1], acc);
              acc = fma((double)w4.z, pr[e + 2], acc);
              acc = fma((double)w4.w, pr[e + 3], acc);
            }
          }
          #pragma unroll
          for (int off = 1; off < 64; off <<= 1) acc += __shfl_xor(acc, off);
        }
        if (lane == 0)
          ctxD[b * C_ + c] = (idx > 0) ? (acc + (double)bout[c]) : 0.0;
      }
    }
    gbar(cnt, ep);
  }
}

extern "C" void kernel_launch(void* const* d_in, const int* in_sizes, int n_in,
                              void* d_out, int out_size, void* d_ws, size_t ws_size,
                              hipStream_t stream) {
  (void)in_sizes; (void)n_in; (void)out_size;
  if (ws_size < WS_BYTES) return;
  const float* data = (const float*)d_in[0];
  const float* W_ih = (const float*)d_in[1];
  const float* W_hh = (const float*)d_in[2];
  const float* b_ih = (const float*)d_in[3];
  const float* b_hh = (const float*)d_in[4];
  const float* Wa   = (const float*)d_in[5];
  const float* ba   = (const float*)d_in[6];
  const float* W1   = (const float*)d_in[7];
  const float* b1   = (const float*)d_in[8];
  const float* W2   = (const float*)d_in[9];
  const float* Wout = (const float*)d_in[10];
  const float* bout = (const float*)d_in[11];
  hipMemsetAsync(d_ws, 0, 4096, stream);         // reset barrier state (replay-safe)
  srnn<<<dim3(NB), dim3(NT), 0, stream>>>(data, W_ih, W_hh, b_ih, b_hh, Wa, ba,
                                          W1, b1, W2, Wout, bout,
                                          (float*)d_out, (float*)d_ws);
}